// Round 7
// baseline (284.116 us; speedup 1.0000x reference)
//
#include <hip/hip_runtime.h>

#define NP    8192
#define NCG   20
#define NC3   8000      // 20^3 unit cells over [0,20)^3
#define SCAP  4608      // cell-sorted occupied-pred capacity (~4096 expected)
#define ECAP  10240     // CSR entry capacity (~8800 expected)
#define CAP   16        // per-row candidate cap
#define INF_U 0xFFFFFFFFu
#define LASTF 0x8000u   // E[e] bit15: last entry of its row
#define COLM  0x1FFFu

// Single fused kernel: bin -> scan -> scatter -> build -> match -> reduce.
// Matching = chain-following Gale-Shapley with common column priority = row
// index; entries allocated in strict row order so atomicMin on the ENTRY
// INDEX implements (row,pos) priority. Fixed point == the reference's serial
// greedy scan (validated absmax=0.0 in rounds 1-6).
__global__ __launch_bounds__(1024)
void spl_all(const float4* __restrict__ pred,
             const float4* __restrict__ truec,
             float* __restrict__ out) {
    __shared__ unsigned int HC[NP];             // 32KB: cell counters/cursors (P1-P4), then H (P6+)
    __shared__ unsigned short cellstart[NC3 + 2]; // 16KB
    __shared__ unsigned short sidx[SCAP];       // 9KB  cell-sorted occupied pred idx
    __shared__ unsigned short E[ECAP];          // 20KB col | LASTF
    __shared__ unsigned short R[ECAP];          // 20KB entry -> row
    __shared__ unsigned short o0r[NP];          // 16KB row -> first entry (0xFFFF = none)
    __shared__ int wt[16];
    __shared__ int ebase;
    __shared__ int noccs;
    __shared__ float redf[2][16];
    __shared__ int redi[16];

    int tid = threadIdx.x;
    int lane = tid & 63, wave = tid >> 6;

    // ---- P1: zero cell counters ----
    for (int c = tid; c < NC3; c += 1024) HC[c] = 0u;
    if (tid == 0) { ebase = 0; noccs = 0; }
    __syncthreads();

    // ---- P2: count occupied pred per cell ----
    int pcell[8];
    #pragma unroll
    for (int k = 0; k < 8; ++k) {
        int i = k * 1024 + tid;
        float4 p = pred[i];
        if (p.w >= 0.5f) {
            int cx = min((int)p.x, NCG - 1);
            int cy = min((int)p.y, NCG - 1);
            int cz = min((int)p.z, NCG - 1);
            pcell[k] = (cz * NCG + cy) * NCG + cx;
            atomicAdd(&HC[pcell[k]], 1u);
        } else pcell[k] = -1;
    }
    __syncthreads();

    // ---- P3: exclusive scan (8000 cells) -> cellstart u16 + HC as u32 cursor ----
    int base8 = tid * 8;
    int loc[8]; int s = 0;
    #pragma unroll
    for (int k = 0; k < 8; ++k) {
        int c = base8 + k;
        int v = (c < NC3) ? (int)HC[c] : 0;
        loc[k] = s; s += v;
    }
    int inc = s;
    #pragma unroll
    for (int o = 1; o < 64; o <<= 1) {
        int t = __shfl_up(inc, o);
        if (lane >= o) inc += t;
    }
    if (lane == 63) wt[wave] = inc;
    __syncthreads();
    if (tid < 16) {
        int v = wt[tid]; int iv = v;
        #pragma unroll
        for (int o = 1; o < 16; o <<= 1) {
            int t = __shfl_up(iv, o);
            if (tid >= o) iv += t;
        }
        wt[tid] = iv - v;
    }
    __syncthreads();
    int eb0 = wt[wave] + inc - s;
    #pragma unroll
    for (int k = 0; k < 8; ++k) {
        int c = base8 + k;
        if (c < NC3) {
            int st = eb0 + loc[k];
            cellstart[c] = (unsigned short)st;
            HC[c] = (unsigned int)st;           // scatter cursor
        }
    }
    if (tid == 1023) cellstart[NC3] = (unsigned short)(wt[15] + inc);
    __syncthreads();

    // ---- P4: scatter occupied pred indices (cell-sorted) ----
    #pragma unroll
    for (int k = 0; k < 8; ++k) {
        if (pcell[k] >= 0) {
            unsigned int slot = atomicAdd(&HC[pcell[k]], 1u);
            if (slot < SCAP) sidx[slot] = (unsigned short)(k * 1024 + tid);
        }
    }
    __syncthreads();

    // ---- P5: build candidates, 1 thread per true row, 8 row batches ----
    for (int b = 0; b < 8; ++b) {
        int r = b * 1024 + tid;
        float4 t = truec[r];
        unsigned long long skey[CAP];
        #pragma unroll
        for (int k = 0; k < CAP; ++k) skey[k] = 0xFFFFFFFFFFFFFFFFull;
        int n = 0;
        bool occ = (t.w >= 0.5f);
        if (occ) {
            int cx = min((int)t.x, NCG - 1);
            int cy = min((int)t.y, NCG - 1);
            int cz = min((int)t.z, NCG - 1);
            int x0 = max(cx - 1, 0), x1 = min(cx + 1, NCG - 1);
            int y0 = max(cy - 1, 0), y1 = min(cy + 1, NCG - 1);
            int z0 = max(cz - 1, 0), z1 = min(cz + 1, NCG - 1);
            for (int zz = z0; zz <= z1; ++zz)
            for (int yy = y0; yy <= y1; ++yy) {
                int cb = (zz * NCG + yy) * NCG;
                int s0 = cellstart[cb + x0];
                int s1 = cellstart[cb + x1 + 1];   // x-contiguous span
                for (int sI = s0; sI < s1; ++sI) {
                    int j = sidx[sI];
                    float4 p = pred[j];
                    float dx = t.x - p.x, dy = t.y - p.y, dz = t.z - p.z;
                    float d = sqrtf(dx * dx + dy * dy + dz * dz);
                    if (d <= 1.0f) {
                        unsigned long long kv =
                            ((unsigned long long)__float_as_uint(d) << 32) | (unsigned)j;
                        #pragma unroll                 // bubble insert, statically indexed
                        for (int k = 0; k < CAP; ++k) {
                            unsigned long long lo = (skey[k] < kv) ? skey[k] : kv;
                            unsigned long long hi = (skey[k] < kv) ? kv : skey[k];
                            skey[k] = lo; kv = hi;
                        }
                        ++n;
                    }
                }
            }
            if (n > CAP) n = CAP;
        }
        unsigned long long bal = __ballot(occ);
        if (lane == 0) atomicAdd(&noccs, (int)__popcll(bal));

        // batch scan of per-row counts -> row-ordered entry offsets
        int incn = n;
        #pragma unroll
        for (int o = 1; o < 64; o <<= 1) {
            int u = __shfl_up(incn, o);
            if (lane >= o) incn += u;
        }
        if (lane == 63) wt[wave] = incn;
        __syncthreads();
        if (tid < 16) {
            int v = wt[tid]; int iv = v;
            #pragma unroll
            for (int o = 1; o < 16; o <<= 1) {
                int u = __shfl_up(iv, o);
                if (tid >= o) iv += u;
            }
            wt[tid] = iv - v;
        }
        __syncthreads();
        int start = ebase + wt[wave] + incn - n;
        int nn = n;
        if (start >= ECAP) nn = 0;
        else if (start + nn > ECAP) nn = ECAP - start;
        o0r[r] = (nn > 0) ? (unsigned short)start : (unsigned short)0xFFFF;
        for (int k = 0; k < nn; ++k) {
            unsigned short col = (unsigned short)(skey[k] & COLM);
            if (k == nn - 1) col |= (unsigned short)LASTF;
            E[start + k] = col;
            R[start + k] = (unsigned short)r;
        }
        __syncthreads();
        if (tid == 1023) ebase += wt[15] + incn;
        __syncthreads();
    }

    // ---- P6: init H over the (dead) cell-counter region ----
    for (int rr = tid; rr < NP; rr += 1024) HC[rr] = INF_U;
    __syncthreads();

    // ---- P7: chain-following matching (2 LDS ops per step) ----
    for (int b = 0; b < 8; ++b) {
        int r = b * 1024 + tid;
        unsigned int e = o0r[r];
        if (e == 0xFFFFu) continue;
        while (true) {
            unsigned int ec = E[e];
            unsigned int col = ec & COLM;
            if (HC[col] < e) {                    // pre-check; sound: H only decreases
                if (ec & LASTF) break;
                ++e; continue;
            }
            unsigned int old = atomicMin(&HC[col], e);
            if (old > e) {
                if (old == INF_U) break;          // claimed a free col: chain ends
                unsigned int eco = E[old];        // displaced row continues at old+1
                if (eco & LASTF) break;
                e = old + 1;
            } else {
                if (ec & LASTF) break;            // lost; advance own list
                ++e;
            }
        }
    }
    __syncthreads();

    // ---- P8: matched-only reduction (fixed order -> deterministic) ----
    float sdist = 0.f, sprob = 0.f;
    int nm = 0;
    for (int j = tid; j < NP; j += 1024) {
        unsigned int h = HC[j];
        if (h != INF_U) {
            int r = R[h];
            float4 t = truec[r];
            float4 pp = pred[j];
            float dx = t.x - pp.x, dy = t.y - pp.y, dz = t.z - pp.z;
            sdist += sqrtf(dx * dx + dy * dy + dz * dz);
            float dp = t.w - pp.w;
            sprob += dp * dp;
            ++nm;
        }
    }
    for (int o = 32; o; o >>= 1) {
        sdist += __shfl_down(sdist, o);
        sprob += __shfl_down(sprob, o);
        nm    += __shfl_down(nm, o);
    }
    if (lane == 0) { redf[0][wave] = sdist; redf[1][wave] = sprob; redi[wave] = nm; }
    __syncthreads();
    if (tid == 0) {
        float S = 0.f, P = 0.f; int NM = 0;
        for (int w = 0; w < 16; ++w) { S += redf[0][w]; P += redf[1][w]; NM += redi[w]; }
        float nmf = (float)NM;
        float unm = (float)noccs - nmf;
        out[0] = (S / nmf + 10.0f * unm) + (P / nmf + unm);
    }
}

extern "C" void kernel_launch(void* const* d_in, const int* in_sizes, int n_in,
                              void* d_out, int out_size, void* d_ws, size_t ws_size,
                              hipStream_t stream) {
    const float4* pred  = (const float4*)d_in[0];
    const float4* truec = (const float4*)d_in[1];
    float* out = (float*)d_out;
    spl_all<<<1, 1024, 0, stream>>>(pred, truec, out);
}

// Round 8
// 67.360 us; speedup vs baseline: 4.2179x; 4.2179x over previous
//
#include <hip/hip_runtime.h>

#define NP      8192
#define CAP     16          // per-row candidate cap (pos fits 4 bits)
#define NCG     20
#define NC3     8000        // 20^3 unit cells over [0,20)^3
#define CELLCAP 8           // fixed slots per cell (P(overflow)~1e-6; validated)
#define NBLK    64          // build blocks
#define ROWS_PB 128         // rows per build block
#define SEG_PB  256         // fixed entry segment per block (deterministic!)
#define ECAP    (NBLK*SEG_PB)   // 16384
#define INF_U   0xFFFFFFFFu

// ---------- K1: zero cell counters + scalars ----------
__global__ void zero_misc(int* __restrict__ cellcnt,
                          int* __restrict__ nocc,
                          int* __restrict__ done) {
    int i = blockIdx.x * 1024 + threadIdx.x;
    if (i < NC3) cellcnt[i] = 0;
    if (i == 0) { *nocc = 0; *done = 0; }
}

// ---------- K2: scatter occupied pred into fixed-capacity cells ----------
__global__ void bin_scatter(const float4* __restrict__ pred,
                            int* __restrict__ cellcnt,
                            float4* __restrict__ spred,
                            int* __restrict__ sidx) {
    int i = blockIdx.x * 256 + threadIdx.x;
    if (i >= NP) return;
    float4 p = pred[i];
    if (p.w < 0.5f) return;
    int cx = min((int)p.x, NCG - 1);
    int cy = min((int)p.y, NCG - 1);
    int cz = min((int)p.z, NCG - 1);
    int c = (cz * NCG + cy) * NCG + cx;
    int rk = atomicAdd(&cellcnt[c], 1);
    if (rk < CELLCAP) {
        spred[c * CELLCAP + rk] = p;
        sidx[c * CELLCAP + rk] = i;
    }
}

// ---------- K3: parallel candidate build + last-block LDS match + reduce ----------
// Matching: chain-following Gale-Shapley, common column priority = row index.
// H[col] = (row<<4)|pos under LDS atomicMin (monotone). Fixed point == the
// reference's serial greedy scan (validated absmax=0.0, rounds 1-7).
__global__ __launch_bounds__(512)
void build_match(const float4* __restrict__ pred,
                 const float4* __restrict__ truec,
                 const float4* __restrict__ spred,
                 const int* __restrict__ sidx,
                 const int* __restrict__ cellcnt,
                 unsigned short* __restrict__ Eg,    // ECAP entry cols
                 unsigned short* __restrict__ o0g,   // row -> entry start (0xFFFF none)
                 unsigned char* __restrict__ cng,    // row -> count
                 int* __restrict__ nocc,
                 int* __restrict__ done,
                 float* __restrict__ out) {
    // build-phase LDS
    __shared__ unsigned long long skey[ROWS_PB][CAP];   // 16KB
    __shared__ int scnt[ROWS_PB];
    __shared__ int sst[ROWS_PB];
    __shared__ int wtot[2];
    // matcher LDS (used by last block only)
    __shared__ unsigned short Es[ECAP];   // 32KB
    __shared__ unsigned short o0s[NP];    // 16KB
    __shared__ unsigned char cn8[NP];     // 8KB
    __shared__ unsigned int Hs[NP];       // 32KB
    __shared__ int amLast;
    __shared__ float redf[2][8];
    __shared__ int redi[8];

    int tid = threadIdx.x;
    int lane = tid & 63, wave = tid >> 6;
    int l = tid & 3, g = tid >> 2;               // 4 lanes per row, 128 rows
    int row = blockIdx.x * ROWS_PB + g;
    if (l == 0) scnt[g] = 0;
    __syncthreads();

    // ---- build candidates (R6-proven scheme) ----
    float4 t = truec[row];
    bool occ = (t.w >= 0.5f);
    unsigned long long bal = __ballot(l == 0 && occ);
    if (lane == 0) atomicAdd(nocc, (int)__popcll(bal));

    if (occ) {
        int cx = min((int)t.x, NCG - 1);
        int cy = min((int)t.y, NCG - 1);
        int cz = min((int)t.z, NCG - 1);
        int x0 = max(cx - 1, 0), x1 = min(cx + 1, NCG - 1);
        for (int sp = l; sp < 9; sp += 4) {
            int zz = cz - 1 + sp / 3;
            int yy = cy - 1 + sp % 3;
            if (zz < 0 || zz >= NCG || yy < 0 || yy >= NCG) continue;
            int cb = (zz * NCG + yy) * NCG;
            for (int x = x0; x <= x1; ++x) {
                int c = cb + x;
                int nc = min(cellcnt[c], CELLCAP);
                int sbase = c * CELLCAP;
                for (int k = 0; k < nc; ++k) {
                    float4 p = spred[sbase + k];
                    float dx = t.x - p.x, dy = t.y - p.y, dz = t.z - p.z;
                    float d = sqrtf(dx * dx + dy * dy + dz * dz);
                    if (d <= 1.0f) {
                        int a = atomicAdd(&scnt[g], 1);
                        if (a < CAP)
                            skey[g][a] = ((unsigned long long)__float_as_uint(d) << 32)
                                         | (unsigned int)sidx[sbase + k];
                    }
                }
            }
        }
    }
    __syncthreads();
    if (l == 0) {
        int n = min(scnt[g], CAP);
        for (int a = 1; a < n; ++a) {            // sort (d asc, j asc) = argmin tie-break
            unsigned long long kv = skey[g][a];
            int b = a - 1;
            while (b >= 0 && skey[g][b] > kv) { skey[g][b + 1] = skey[g][b]; --b; }
            skey[g][b + 1] = kv;
        }
        scnt[g] = n;
    }
    __syncthreads();
    // scan of 128 row-counts (2 waves) -> local offsets in this block's segment
    if (tid < ROWS_PB) {
        int n = scnt[tid];
        int inc = n;
        #pragma unroll
        for (int o = 1; o < 64; o <<= 1) {
            int u = __shfl_up(inc, o);
            if (lane >= o) inc += u;
        }
        if (lane == 63) wtot[wave] = inc;
        sst[tid] = inc - n;                      // wave-local exclusive
    }
    __syncthreads();
    if (tid < ROWS_PB) {
        int st = sst[tid] + ((tid >= 64) ? wtot[0] : 0);
        int n = scnt[tid];
        int nn = n;
        if (st >= SEG_PB) nn = 0;                // P ~ 1e-13 guard
        else if (st + nn > SEG_PB) nn = SEG_PB - st;
        sst[tid] = st;
        scnt[tid] = nn;
        int r = blockIdx.x * ROWS_PB + tid;
        int gstart = blockIdx.x * SEG_PB + st;
        o0g[r] = (nn > 0) ? (unsigned short)gstart : (unsigned short)0xFFFF;
        cng[r] = (unsigned char)nn;
    }
    __syncthreads();
    {
        int gstart = blockIdx.x * SEG_PB + sst[g];
        int nn = scnt[g];
        for (int k = l; k < nn; k += 4)
            Eg[gstart + k] = (unsigned short)(skey[g][k] & 0x1FFFu);
    }

    // ---- last-block handoff ----
    __threadfence();                             // release this block's stores
    __syncthreads();
    if (tid == 0) amLast = (atomicAdd(done, 1) == NBLK - 1);
    __syncthreads();
    if (!amLast) return;
    __threadfence();                             // acquire remote blocks' stores

    // ---- stage everything into LDS (content is replay-deterministic) ----
    for (int x = tid; x < ECAP / 2; x += 512)
        ((unsigned int*)Es)[x] = ((const unsigned int*)Eg)[x];
    for (int x = tid; x < NP / 2; x += 512)
        ((unsigned int*)o0s)[x] = ((const unsigned int*)o0g)[x];
    for (int x = tid; x < NP / 4; x += 512)
        ((unsigned int*)cn8)[x] = ((const unsigned int*)cng)[x];
    for (int r = tid; r < NP; r += 512) Hs[r] = INF_U;
    __syncthreads();

    // ---- chain-following matching ----
    for (int r0 = tid; r0 < NP; r0 += 512) {
        int n = cn8[r0];
        if (!n) continue;
        int r = r0, p = 0;
        int e = o0s[r0];
        while (true) {
            unsigned int col = Es[e];
            unsigned int key = ((unsigned int)r << 4) | (unsigned int)p;
            if (Hs[col] < key) {                 // sound pre-check: H only decreases
                if (++p >= n) break;
                ++e; continue;
            }
            unsigned int old = atomicMin(&Hs[col], key);
            if (old > key) {
                if (old == INF_U) break;         // claimed free col: chain ends
                r = (int)(old >> 4);             // displaced row continues
                p = (int)(old & 15u) + 1;
                n = cn8[r];
                if (p >= n) break;
                e = o0s[r] + p;
            } else {
                if (++p >= n) break;             // better row holds it (permanent)
                ++e;
            }
        }
    }
    __syncthreads();

    // ---- matched-only reduction (fixed order -> deterministic) ----
    float sdist = 0.f, sprob = 0.f;
    int nm = 0;
    for (int j = tid; j < NP; j += 512) {
        unsigned int h = Hs[j];
        if (h != INF_U) {
            int r = (int)(h >> 4);
            float4 tt = truec[r];
            float4 pp = pred[j];
            float dx = tt.x - pp.x, dy = tt.y - pp.y, dz = tt.z - pp.z;
            sdist += sqrtf(dx * dx + dy * dy + dz * dz);
            float dp = tt.w - pp.w;
            sprob += dp * dp;
            ++nm;
        }
    }
    for (int o = 32; o; o >>= 1) {
        sdist += __shfl_down(sdist, o);
        sprob += __shfl_down(sprob, o);
        nm    += __shfl_down(nm, o);
    }
    if (lane == 0) { redf[0][wave] = sdist; redf[1][wave] = sprob; redi[wave] = nm; }
    __syncthreads();
    if (tid == 0) {
        float S = 0.f, P = 0.f; int NM = 0;
        for (int w = 0; w < 8; ++w) { S += redf[0][w]; P += redf[1][w]; NM += redi[w]; }
        float nmf = (float)NM;
        float unm = (float)(*nocc) - nmf;
        out[0] = (S / nmf + 10.0f * unm) + (P / nmf + unm);
    }
}

extern "C" void kernel_launch(void* const* d_in, const int* in_sizes, int n_in,
                              void* d_out, int out_size, void* d_ws, size_t ws_size,
                              hipStream_t stream) {
    const float4* pred  = (const float4*)d_in[0];
    const float4* truec = (const float4*)d_in[1];
    float* out = (float*)d_out;

    float4* spred       = (float4*)d_ws;                        // NC3*CELLCAP float4
    int* sidx           = (int*)(spred + NC3 * CELLCAP);        // NC3*CELLCAP
    int* cellcnt        = sidx + NC3 * CELLCAP;                 // NC3
    int* nocc           = cellcnt + NC3;                        // 1
    int* done           = nocc + 1;                             // 1
    unsigned short* Eg  = (unsigned short*)(done + 1);          // ECAP
    unsigned short* o0g = Eg + ECAP;                            // NP
    unsigned char* cng  = (unsigned char*)(o0g + NP);           // NP

    zero_misc  <<<8,    1024, 0, stream>>>(cellcnt, nocc, done);
    bin_scatter<<<32,   256,  0, stream>>>(pred, cellcnt, spred, sidx);
    build_match<<<NBLK, 512,  0, stream>>>(pred, truec, spred, sidx, cellcnt,
                                           Eg, o0g, cng, nocc, done, out);
}

// Round 9
// 45.589 us; speedup vs baseline: 6.2321x; 1.4775x over previous
//
#include <hip/hip_runtime.h>

#define NP    8192
#define NCG   20
#define NC3   8000      // 20^3 unit cells over [0,20)^3
#define SCAP  4608      // compact occupied-pred capacity (expected ~4096, +11 sigma)
#define ECAP  10240     // CSR entry capacity (expected ~8800, +9 sigma)
#define CAP   16        // per-row candidate cap (pos fits 4 bits)
#define INF_U 0xFFFFFFFFu

// ---------- K1: bin (1 block): count + scan + scatter -> compact spred ----------
// spred[slot] = (x, y, z, int_as_float(original_index))
__global__ __launch_bounds__(1024)
void bin_all(const float4* __restrict__ pred,
             int* __restrict__ gstart,
             float4* __restrict__ spred,
             int* __restrict__ ecnt,
             int* __restrict__ nocc) {
    __shared__ int cc[NC3];
    __shared__ int wt[16];
    int tid = threadIdx.x;
    int lane = tid & 63, wave = tid >> 6;
    if (tid == 0) { *ecnt = 0; *nocc = 0; }
    for (int c = tid; c < NC3; c += 1024) cc[c] = 0;
    __syncthreads();

    float4 p[8]; int cell[8], rk[8];
    #pragma unroll
    for (int k = 0; k < 8; ++k) {
        int i = k * 1024 + tid;
        p[k] = pred[i];
        if (p[k].w >= 0.5f) {
            int cx = min((int)p[k].x, NCG - 1);
            int cy = min((int)p[k].y, NCG - 1);
            int cz = min((int)p[k].z, NCG - 1);
            cell[k] = (cz * NCG + cy) * NCG + cx;
            rk[k] = atomicAdd(&cc[cell[k]], 1);
        } else cell[k] = -1;
    }
    __syncthreads();

    // exclusive scan: per-thread serial(8) + wave shfl + 16-wave combine
    int base8 = tid * 8;
    int loc[8]; int s = 0;
    #pragma unroll
    for (int k = 0; k < 8; ++k) {
        int c = base8 + k;
        int v = (c < NC3) ? cc[c] : 0;
        loc[k] = s; s += v;
    }
    int inc = s;
    #pragma unroll
    for (int o = 1; o < 64; o <<= 1) {
        int t = __shfl_up(inc, o);
        if (lane >= o) inc += t;
    }
    if (lane == 63) wt[wave] = inc;
    __syncthreads();
    if (tid < 16) {
        int v = wt[tid]; int iv = v;
        #pragma unroll
        for (int o = 1; o < 16; o <<= 1) {
            int t = __shfl_up(iv, o);
            if (tid >= o) iv += t;
        }
        wt[tid] = iv - v;
    }
    __syncthreads();
    int eb = wt[wave] + inc - s;
    #pragma unroll
    for (int k = 0; k < 8; ++k) {
        int c = base8 + k;
        if (c < NC3) { int v = eb + loc[k]; gstart[c] = v; cc[c] = v; }
    }
    if (tid == 1023) gstart[NC3] = wt[15] + inc;
    __syncthreads();

    #pragma unroll
    for (int k = 0; k < 8; ++k) {
        if (cell[k] >= 0) {
            int slot = cc[cell[k]] + rk[k];
            if (slot < SCAP) {
                float4 v = p[k];
                v.w = __int_as_float(k * 1024 + tid);   // pack original index
                spred[slot] = v;
            }
        }
    }
}

// ---------- K2: candidate build, all search traffic in LDS ----------
// 128 blocks x 256 threads; 4 lanes per row, 64 rows/block. Stage compact
// pred + cell starts into LDS first (coalesced), then search at LDS latency.
__global__ __launch_bounds__(256)
void build_cands(const float4* __restrict__ truec,
                 const float4* __restrict__ spred,
                 const int* __restrict__ gstart,
                 int* __restrict__ ecnt,
                 int* __restrict__ nocc,
                 unsigned short* __restrict__ o0g,   // row -> entry start (0xFFFF none)
                 unsigned char* __restrict__ cng,    // row -> count
                 unsigned short* __restrict__ Eg) {  // entry cols (sorted per row)
    __shared__ float4 spredL[SCAP];                 // 73.7KB
    __shared__ unsigned short gst[NC3 + 1];         // 16KB
    __shared__ unsigned long long skey[64][CAP];    // 8KB
    __shared__ int scnt[64];
    __shared__ int sst[64];
    __shared__ int sbase;
    int tid = threadIdx.x;
    int l = tid & 3, g = tid >> 2;
    int row = blockIdx.x * 64 + g;

    int ntot = gstart[NC3];
    if (ntot > SCAP) ntot = SCAP;
    for (int x = tid; x <= NC3; x += 256) gst[x] = (unsigned short)gstart[x];
    for (int x = tid; x < ntot; x += 256) spredL[x] = spred[x];
    if (l == 0) scnt[g] = 0;
    __syncthreads();

    float4 t = truec[row];
    bool occ = (t.w >= 0.5f);
    unsigned long long bal = __ballot(l == 0 && occ);
    if ((tid & 63) == 0) atomicAdd(nocc, (int)__popcll(bal));

    if (occ) {
        int cx = min((int)t.x, NCG - 1);
        int cy = min((int)t.y, NCG - 1);
        int cz = min((int)t.z, NCG - 1);
        int x0 = max(cx - 1, 0), x1 = min(cx + 1, NCG - 1);
        for (int sp = l; sp < 9; sp += 4) {
            int zz = cz - 1 + sp / 3;
            int yy = cy - 1 + sp % 3;
            if (zz < 0 || zz >= NCG || yy < 0 || yy >= NCG) continue;
            int cb = (zz * NCG + yy) * NCG;
            int s0 = gst[cb + x0];
            int s1 = gst[cb + x1 + 1];              // x-contiguous span
            for (int s = s0; s < s1; ++s) {
                float4 p = spredL[s];
                float dx = t.x - p.x, dy = t.y - p.y, dz = t.z - p.z;
                float d = sqrtf(dx * dx + dy * dy + dz * dz);
                if (d <= 1.0f) {
                    int a = atomicAdd(&scnt[g], 1);
                    if (a < CAP)
                        skey[g][a] = ((unsigned long long)__float_as_uint(d) << 32)
                                     | (unsigned int)__float_as_int(p.w);
                }
            }
        }
    }
    __syncthreads();
    if (l == 0) {
        int n = min(scnt[g], CAP);
        for (int a = 1; a < n; ++a) {               // (d asc, j asc) = argmin tie-break
            unsigned long long kv = skey[g][a];
            int b = a - 1;
            while (b >= 0 && skey[g][b] > kv) { skey[g][b + 1] = skey[g][b]; --b; }
            skey[g][b + 1] = kv;
        }
        scnt[g] = n;
    }
    __syncthreads();
    // wave 0 scans the 64 row-counts and allocates the block's CSR segment
    if (tid < 64) {
        int n = scnt[tid];
        int inc = n;
        #pragma unroll
        for (int o = 1; o < 64; o <<= 1) {
            int u = __shfl_up(inc, o);
            if (tid >= o) inc += u;
        }
        int total = __shfl(inc, 63);
        int b = 0;
        if (tid == 0) b = atomicAdd(ecnt, total);
        b = __shfl(b, 0);
        if (tid == 0) sbase = b;
        int st = b + inc - n;
        int nn = n;
        if (st >= ECAP) nn = 0;
        else if (st + nn > ECAP) nn = ECAP - st;
        sst[tid] = st;
        scnt[tid] = nn;
        int r = blockIdx.x * 64 + tid;
        o0g[r] = (nn > 0) ? (unsigned short)st : (unsigned short)0xFFFF;
        cng[r] = (unsigned char)nn;
    }
    __syncthreads();
    int st = sst[g], nn = scnt[g];
    for (int k = l; k < nn; k += 4)
        Eg[st + k] = (unsigned short)(skey[g][k] & 0x1FFFu);
}

// ---------- K3: LDS chain-following Gale-Shapley + matched-only reduction ----------
// H[col] = (row<<4)|pos under LDS atomicMin (monotone-decreasing). Fixed point
// == the reference's serial greedy scan (validated absmax=0.0, rounds 1-8).
__global__ __launch_bounds__(1024)
void match_reduce(const float4* __restrict__ pred,
                  const float4* __restrict__ truec,
                  const unsigned short* __restrict__ o0g,
                  const unsigned char* __restrict__ cng,
                  const unsigned short* __restrict__ Eg,
                  const int* __restrict__ ecnt,
                  const int* __restrict__ nocc,
                  float* __restrict__ out) {
    __shared__ unsigned short E[ECAP];    // 20KB
    __shared__ unsigned short o0s[NP];    // 16KB
    __shared__ unsigned char cn8[NP];     // 8KB
    __shared__ unsigned int Hs[NP];       // 32KB
    __shared__ float redf[2][16];
    __shared__ int redi[16];
    int tid = threadIdx.x;
    int ne = *ecnt; if (ne > ECAP) ne = ECAP;
    for (int x = tid; x < (ne + 1) / 2; x += 1024)
        ((unsigned int*)E)[x] = ((const unsigned int*)Eg)[x];
    for (int x = tid; x < NP / 2; x += 1024)
        ((unsigned int*)o0s)[x] = ((const unsigned int*)o0g)[x];
    for (int x = tid; x < NP / 4; x += 1024)
        ((unsigned int*)cn8)[x] = ((const unsigned int*)cng)[x];
    for (int r = tid; r < NP; r += 1024) Hs[r] = INF_U;
    __syncthreads();

    for (int r0 = tid; r0 < NP; r0 += 1024) {
        int n = cn8[r0];
        if (!n) continue;
        int r = r0, p = 0;
        int e = o0s[r0];
        while (true) {
            unsigned int col = E[e];
            unsigned int key = ((unsigned int)r << 4) | (unsigned int)p;
            if (Hs[col] < key) {                    // sound pre-check: H only decreases
                if (++p >= n) break;
                ++e; continue;
            }
            unsigned int old = atomicMin(&Hs[col], key);
            if (old > key) {
                if (old == INF_U) break;            // claimed a free col: chain ends
                r = (int)(old >> 4);                // displaced row continues
                p = (int)(old & 15u) + 1;
                n = cn8[r];
                if (p >= n) break;
                e = o0s[r] + p;
            } else {
                if (++p >= n) break;                // better row holds it (permanent)
                ++e;
            }
        }
    }
    __syncthreads();

    // matched-only reduction (fixed order -> deterministic)
    float sdist = 0.f, sprob = 0.f;
    int nm = 0;
    for (int j = tid; j < NP; j += 1024) {
        unsigned int h = Hs[j];
        if (h != INF_U) {
            int r = (int)(h >> 4);
            float4 tt = truec[r];
            float4 pp = pred[j];
            float dx = tt.x - pp.x, dy = tt.y - pp.y, dz = tt.z - pp.z;
            sdist += sqrtf(dx * dx + dy * dy + dz * dz);
            float dp = tt.w - pp.w;
            sprob += dp * dp;
            ++nm;
        }
    }
    for (int o = 32; o; o >>= 1) {
        sdist += __shfl_down(sdist, o);
        sprob += __shfl_down(sprob, o);
        nm    += __shfl_down(nm, o);
    }
    int wave = tid >> 6, lane = tid & 63;
    if (lane == 0) { redf[0][wave] = sdist; redf[1][wave] = sprob; redi[wave] = nm; }
    __syncthreads();
    if (tid == 0) {
        float S = 0.f, P = 0.f; int NM = 0;
        for (int w = 0; w < 16; ++w) { S += redf[0][w]; P += redf[1][w]; NM += redi[w]; }
        float nmf = (float)NM;
        float unm = (float)(*nocc) - nmf;
        out[0] = (S / nmf + 10.0f * unm) + (P / nmf + unm);
    }
}

extern "C" void kernel_launch(void* const* d_in, const int* in_sizes, int n_in,
                              void* d_out, int out_size, void* d_ws, size_t ws_size,
                              hipStream_t stream) {
    const float4* pred  = (const float4*)d_in[0];
    const float4* truec = (const float4*)d_in[1];
    float* out = (float*)d_out;

    float4* spred       = (float4*)d_ws;                    // SCAP float4
    int* gstart         = (int*)(spred + SCAP);             // NC3+1
    int* ecnt           = gstart + NC3 + 1;                 // 1
    int* nocc           = ecnt + 1;                         // 1
    unsigned short* o0g = (unsigned short*)(nocc + 1);      // NP
    unsigned char* cng  = (unsigned char*)(o0g + NP);       // NP
    unsigned short* Eg  = (unsigned short*)(cng + NP);      // ECAP

    bin_all     <<<1,   1024, 0, stream>>>(pred, gstart, spred, ecnt, nocc);
    build_cands <<<128, 256,  0, stream>>>(truec, spred, gstart, ecnt, nocc, o0g, cng, Eg);
    match_reduce<<<1,   1024, 0, stream>>>(pred, truec, o0g, cng, Eg, ecnt, nocc, out);
}

// Round 10
// 38.015 us; speedup vs baseline: 7.4737x; 1.1992x over previous
//
#include <hip/hip_runtime.h>

#define NP      8192
#define NCG     20
#define NC3     8000        // 20^3 unit cells over [0,20)^3
#define SCAP    4608        // compact occupied-pred capacity (~4096 expected, +11 sigma)
#define NBLK    64          // build blocks
#define ROWS_PB 128         // rows per build block (512 threads, 4 lanes/row)
#define SEG_PB  256         // fixed entry segment per block (deterministic, ~137 expected)
#define ECAP    (NBLK*SEG_PB)   // 16384
#define CAP     16          // per-row candidate cap (pos fits 4 bits)
#define INF_U   0xFFFFFFFFu

// ---------- K1: self-binning candidate build (64 blocks x 512 threads) ----------
// Each block builds its own LDS bin structure from scratch (coalesced L2 reads),
// then searches the 27-cell neighborhoods of its 128 true rows at LDS latency.
// Entries land in a FIXED per-block segment -> no global counters, no zeroing.
__global__ __launch_bounds__(512)
void build_cands(const float4* __restrict__ pred,
                 const float4* __restrict__ truec,
                 unsigned short* __restrict__ o0g,   // row -> entry start | 0xFFFE occ-none | 0xFFFF unocc
                 unsigned char* __restrict__ cng,    // row -> candidate count
                 unsigned short* __restrict__ Eg) {  // ECAP entry cols (sorted per row)
    __shared__ float4 spredL[SCAP];                  // 73.7KB compact occupied pred (idx in .w)
    __shared__ int cc[NC3];                          // 32KB  cell counters (pass1) / scan src
    __shared__ unsigned short cellstart[NC3 + 1];    // 16KB  cell start offsets
    __shared__ unsigned long long skey[ROWS_PB][CAP];// 16KB  per-row (d,j) keys
    __shared__ int scnt[ROWS_PB];
    __shared__ int sst[ROWS_PB];
    __shared__ int wt[8];
    __shared__ int wtot[2];
    int tid = threadIdx.x;
    int lane = tid & 63, wave = tid >> 6;

    for (int c = tid; c < NC3; c += 512) cc[c] = 0;
    __syncthreads();

    // pass 1: count occupied points per cell, remember (cell, rank)
    int cell[16], rk[16];
    #pragma unroll
    for (int k = 0; k < 16; ++k) {
        int i = k * 512 + tid;
        float4 p = pred[i];
        if (p.w >= 0.5f) {
            int cx = min((int)p.x, NCG - 1);
            int cy = min((int)p.y, NCG - 1);
            int cz = min((int)p.z, NCG - 1);
            cell[k] = (cz * NCG + cy) * NCG + cx;
            rk[k] = atomicAdd(&cc[cell[k]], 1);
        } else cell[k] = -1;
    }
    __syncthreads();

    // exclusive scan of 8000 cell counts (serial-16 + wave shfl + 8-wave combine)
    int base16 = tid * 16;
    int loc[16]; int s = 0;
    #pragma unroll
    for (int k = 0; k < 16; ++k) {
        int c = base16 + k;
        int v = (c < NC3) ? cc[c] : 0;
        loc[k] = s; s += v;
    }
    int inc = s;
    #pragma unroll
    for (int o = 1; o < 64; o <<= 1) {
        int t = __shfl_up(inc, o);
        if (lane >= o) inc += t;
    }
    if (lane == 63) wt[wave] = inc;
    __syncthreads();
    if (tid < 8) {
        int v = wt[tid]; int iv = v;
        #pragma unroll
        for (int o = 1; o < 8; o <<= 1) {
            int t = __shfl_up(iv, o);
            if (tid >= o) iv += t;
        }
        wt[tid] = iv - v;
    }
    __syncthreads();
    int eb = wt[wave] + inc - s;
    #pragma unroll
    for (int k = 0; k < 16; ++k) {
        int c = base16 + k;
        if (c < NC3) cellstart[c] = (unsigned short)(eb + loc[k]);
    }
    if (tid == 511) cellstart[NC3] = (unsigned short)(wt[7] + inc);
    __syncthreads();

    // pass 2: scatter (slot = cellstart + saved rank; no cursors needed)
    #pragma unroll
    for (int k = 0; k < 16; ++k) {
        if (cell[k] >= 0) {
            int slot = (int)cellstart[cell[k]] + rk[k];
            if (slot < SCAP) {
                int i = k * 512 + tid;
                float4 v = pred[i];
                v.w = __int_as_float(i);         // pack original index
                spredL[slot] = v;
            }
        }
    }
    int l = tid & 3, g = tid >> 2;               // 4 lanes per row
    int row = blockIdx.x * ROWS_PB + g;
    if (l == 0) scnt[g] = 0;
    __syncthreads();

    // search: 27-cell neighborhood at LDS latency
    float4 t = truec[row];
    if (t.w >= 0.5f) {
        int cx = min((int)t.x, NCG - 1);
        int cy = min((int)t.y, NCG - 1);
        int cz = min((int)t.z, NCG - 1);
        int x0 = max(cx - 1, 0), x1 = min(cx + 1, NCG - 1);
        for (int sp = l; sp < 9; sp += 4) {
            int zz = cz - 1 + sp / 3;
            int yy = cy - 1 + sp % 3;
            if (zz < 0 || zz >= NCG || yy < 0 || yy >= NCG) continue;
            int cb = (zz * NCG + yy) * NCG;
            int s0 = cellstart[cb + x0];
            int s1 = cellstart[cb + x1 + 1];     // x-contiguous span
            for (int si = s0; si < s1; ++si) {
                float4 p = spredL[si];
                float dx = t.x - p.x, dy = t.y - p.y, dz = t.z - p.z;
                float d = sqrtf(dx * dx + dy * dy + dz * dz);
                if (d <= 1.0f) {
                    int a = atomicAdd(&scnt[g], 1);
                    if (a < CAP)
                        skey[g][a] = ((unsigned long long)__float_as_uint(d) << 32)
                                     | (unsigned int)__float_as_int(p.w);
                }
            }
        }
    }
    __syncthreads();
    if (l == 0) {
        int n = min(scnt[g], CAP);
        for (int a = 1; a < n; ++a) {            // (d asc, j asc) = argmin tie-break
            unsigned long long kv = skey[g][a];
            int b = a - 1;
            while (b >= 0 && skey[g][b] > kv) { skey[g][b + 1] = skey[g][b]; --b; }
            skey[g][b + 1] = kv;
        }
        scnt[g] = n;
    }
    __syncthreads();
    // allocate within the block's FIXED segment (2-wave scan of 128 counts)
    if (tid < ROWS_PB) {
        int n = scnt[tid];
        int inc2 = n;
        #pragma unroll
        for (int o = 1; o < 64; o <<= 1) {
            int u = __shfl_up(inc2, o);
            if (lane >= o) inc2 += u;
        }
        if (lane == 63) wtot[wave] = inc2;
        sst[tid] = inc2 - n;
    }
    __syncthreads();
    if (tid < ROWS_PB) {
        int st = sst[tid] + ((tid >= 64) ? wtot[0] : 0);
        int n = scnt[tid];
        int nn = n;
        if (st >= SEG_PB) nn = 0;                // P ~ 1e-10 guard
        else if (st + nn > SEG_PB) nn = SEG_PB - st;
        sst[tid] = st;
        scnt[tid] = nn;
        int r = blockIdx.x * ROWS_PB + tid;
        bool occ2 = (truec[r].w >= 0.5f);
        unsigned short o0v;
        if (nn > 0) o0v = (unsigned short)(blockIdx.x * SEG_PB + st);
        else o0v = occ2 ? (unsigned short)0xFFFE : (unsigned short)0xFFFF;
        o0g[r] = o0v;
        cng[r] = (unsigned char)nn;
    }
    __syncthreads();
    {
        int st = blockIdx.x * SEG_PB + sst[g];
        int nn = scnt[g];
        for (int k = l; k < nn; k += 4)
            Eg[st + k] = (unsigned short)(skey[g][k] & 0x1FFFu);
    }
}

// ---------- K2: LDS chain-following Gale-Shapley + matched-only reduction ----------
// H[col] = (row<<4)|pos under LDS atomicMin (monotone-decreasing). Fixed point
// == the reference's serial greedy scan (validated absmax=0.0, rounds 1-9).
__global__ __launch_bounds__(1024)
void match_reduce(const float4* __restrict__ pred,
                  const float4* __restrict__ truec,
                  const unsigned short* __restrict__ o0g,
                  const unsigned char* __restrict__ cng,
                  const unsigned short* __restrict__ Eg,
                  float* __restrict__ out) {
    __shared__ unsigned short E[ECAP];    // 32KB
    __shared__ unsigned short o0s[NP];    // 16KB
    __shared__ unsigned char cn8[NP];     // 8KB
    __shared__ unsigned int Hs[NP];       // 32KB
    __shared__ float redf[2][16];
    __shared__ int redi[2][16];
    int tid = threadIdx.x;
    for (int x = tid; x < ECAP / 2; x += 1024)
        ((unsigned int*)E)[x] = ((const unsigned int*)Eg)[x];
    for (int x = tid; x < NP / 2; x += 1024)
        ((unsigned int*)o0s)[x] = ((const unsigned int*)o0g)[x];
    for (int x = tid; x < NP / 4; x += 1024)
        ((unsigned int*)cn8)[x] = ((const unsigned int*)cng)[x];
    for (int r = tid; r < NP; r += 1024) Hs[r] = INF_U;
    __syncthreads();

    int mynocc = 0;
    for (int r0 = tid; r0 < NP; r0 += 1024) {
        if (o0s[r0] != 0xFFFFu) ++mynocc;        // occupied true row
        int n = cn8[r0];
        if (!n) continue;
        int r = r0, p = 0;
        int e = o0s[r0];
        while (true) {
            unsigned int col = E[e];
            unsigned int key = ((unsigned int)r << 4) | (unsigned int)p;
            if (Hs[col] < key) {                 // sound pre-check: H only decreases
                if (++p >= n) break;
                ++e; continue;
            }
            unsigned int old = atomicMin(&Hs[col], key);
            if (old > key) {
                if (old == INF_U) break;         // claimed a free col: chain ends
                r = (int)(old >> 4);             // displaced row continues
                p = (int)(old & 15u) + 1;
                n = cn8[r];
                if (p >= n) break;
                e = o0s[r] + p;
            } else {
                if (++p >= n) break;             // better row holds it (permanent)
                ++e;
            }
        }
    }
    __syncthreads();

    // matched-only reduction (fixed order -> deterministic)
    float sdist = 0.f, sprob = 0.f;
    int nm = 0;
    for (int j = tid; j < NP; j += 1024) {
        unsigned int h = Hs[j];
        if (h != INF_U) {
            int r = (int)(h >> 4);
            float4 tt = truec[r];
            float4 pp = pred[j];
            float dx = tt.x - pp.x, dy = tt.y - pp.y, dz = tt.z - pp.z;
            sdist += sqrtf(dx * dx + dy * dy + dz * dz);
            float dp = tt.w - pp.w;
            sprob += dp * dp;
            ++nm;
        }
    }
    for (int o = 32; o; o >>= 1) {
        sdist += __shfl_down(sdist, o);
        sprob += __shfl_down(sprob, o);
        nm    += __shfl_down(nm, o);
        mynocc += __shfl_down(mynocc, o);
    }
    int wave = tid >> 6, lane = tid & 63;
    if (lane == 0) {
        redf[0][wave] = sdist; redf[1][wave] = sprob;
        redi[0][wave] = nm;    redi[1][wave] = mynocc;
    }
    __syncthreads();
    if (tid == 0) {
        float S = 0.f, P = 0.f; int NM = 0, NO = 0;
        for (int w = 0; w < 16; ++w) {
            S += redf[0][w]; P += redf[1][w];
            NM += redi[0][w]; NO += redi[1][w];
        }
        float nmf = (float)NM;
        float unm = (float)NO - nmf;
        out[0] = (S / nmf + 10.0f * unm) + (P / nmf + unm);
    }
}

extern "C" void kernel_launch(void* const* d_in, const int* in_sizes, int n_in,
                              void* d_out, int out_size, void* d_ws, size_t ws_size,
                              hipStream_t stream) {
    const float4* pred  = (const float4*)d_in[0];
    const float4* truec = (const float4*)d_in[1];
    float* out = (float*)d_out;

    unsigned short* o0g = (unsigned short*)d_ws;        // NP u16
    unsigned char* cng  = (unsigned char*)(o0g + NP);   // NP u8
    unsigned short* Eg  = (unsigned short*)(cng + NP);  // ECAP u16

    build_cands <<<NBLK, 512,  0, stream>>>(pred, truec, o0g, cng, Eg);
    match_reduce<<<1,    1024, 0, stream>>>(pred, truec, o0g, cng, Eg, out);
}